// Round 1
// baseline (23439.568 us; speedup 1.0000x reference)
//
#include <hip/hip_runtime.h>

// Residual VQ, bit-exact replication of the numpy reference's fp32 rounding.
// B=16 S=2048 D=64 K=8 M=2048.
//
// Numerics contract (must match numpy, see session notes):
//  - r2/c2: numpy pairwise_sum 8-accumulator order, no FMA contraction
//  - cross: numpy einsum baseline-SSE order: 4 chains (d mod 4), per 16-block
//           offsets {12,8,4,0}+j, blocks ascending, hsum (L0+L1)+(L2+L3)
//  - t = fl(r2 - 2*cross) via fmaf(-2,cross,r2); d2 = fl(t + c2)
//  - argmin: first occurrence (strict <, ties -> smaller index)

#define BB 16
#define SS 2048
#define DD 64
#define KK 8
#define MM 2048
#define NPTS (BB * SS)      // 32768
#define QSIZE (NPTS * DD)   // 2097152

// ---- prep: c2[k][m] (numpy pairwise) + codebook transpose to (K, D, M) ----
__global__ __launch_bounds__(256) void rvq_prep(const float* __restrict__ cb,
                                                float* __restrict__ cbt,
                                                float* __restrict__ c2) {
#pragma clang fp contract(off)
    int tid = blockIdx.x * 256 + threadIdx.x;  // 0 .. K*M-1
    const float* row = cb + (size_t)tid * DD;
    float v[DD];
#pragma unroll
    for (int d = 0; d < DD; ++d) v[d] = row[d];
    float r[8];
#pragma unroll
    for (int j = 0; j < 8; ++j) r[j] = v[j] * v[j];
#pragma unroll
    for (int i = 8; i < DD; i += 8) {
#pragma unroll
        for (int j = 0; j < 8; ++j) { float t = v[i + j] * v[i + j]; r[j] += t; }
    }
    float s = ((r[0] + r[1]) + (r[2] + r[3])) + ((r[4] + r[5]) + (r[6] + r[7]));
    c2[tid] = s;

    int k = tid >> 11;           // tid / M
    int m = tid & (MM - 1);      // tid % M
    float* ct = cbt + (size_t)k * DD * MM + m;
#pragma unroll
    for (int d = 0; d < DD; ++d) ct[(size_t)d * MM] = v[d];
}

// ---- one RVQ step: argmin over M for 32768 points, update residual ----
// grid 1024 blocks x 256 threads; 4 waves/block; 8 points/wave.
__global__ __launch_bounds__(256) void rvq_step(const float* __restrict__ res_in,
                                                float* __restrict__ res_out,
                                                const float* __restrict__ cbk,   // (M,D) original, this k
                                                const float* __restrict__ cbtk,  // (D,M) transposed, this k
                                                const float* __restrict__ c2k,   // (M,) this k
                                                float* __restrict__ idx_out) {   // (NPTS,) this k
#pragma clang fp contract(off)
    const int lane = threadIdx.x & 63;
    const int wave = threadIdx.x >> 6;
    const int pbase = blockIdx.x * 32 + wave * 8;

    // --- r2 per point, numpy pairwise: 8 lanes per point, lane = p*8 + j ---
    const int pj = lane >> 3;
    const int jj = lane & 7;
    const float* rr = res_in + (size_t)(pbase + pj) * DD;
    float a0 = rr[jj];
    float acc = a0 * a0;
#pragma unroll
    for (int i = 8; i < DD; i += 8) { float av = rr[i + jj]; float t = av * av; acc += t; }
    // ((r0+r1)+(r2+r3))+((r4+r5)+(r6+r7)) — xor tree is bitwise-equal (commutativity only)
    acc += __shfl_xor(acc, 1);
    acc += __shfl_xor(acc, 2);
    acc += __shfl_xor(acc, 4);
    float r2v[8];
#pragma unroll
    for (int p = 0; p < 8; ++p) r2v[p] = __shfl(acc, p * 8);

    float best[8];
    int bidx[8];
#pragma unroll
    for (int p = 0; p < 8; ++p) { best[p] = __builtin_inff(); bidx[p] = 0; }

#pragma unroll 1
    for (int t = 0; t < MM / 64; ++t) {
        const int m = t * 64 + lane;
        const float c2m = c2k[m];
        float ch[8][4];
#pragma unroll
        for (int p = 0; p < 8; ++p) {
#pragma unroll
            for (int j = 0; j < 4; ++j) ch[p][j] = 0.0f;
        }
        // einsum chain order: per 16-block, groups at offsets 12,8,4,0; 4 chains (j = d mod 4)
#pragma unroll
        for (int b = 0; b < DD; b += 16) {
#pragma unroll
            for (int g = 3; g >= 0; --g) {
#pragma unroll
                for (int j = 0; j < 4; ++j) {
                    const int d = b + g * 4 + j;
                    const float cv = cbtk[(size_t)d * MM + m];
#pragma unroll
                    for (int p = 0; p < 8; ++p) {
                        const float rv = res_in[(size_t)(pbase + p) * DD + d];  // wave-uniform -> s_load
                        float tp = rv * cv;   // rounded mul (no contraction)
                        ch[p][j] += tp;       // rounded add
                    }
                }
            }
        }
#pragma unroll
        for (int p = 0; p < 8; ++p) {
            float cross = (ch[p][0] + ch[p][1]) + (ch[p][2] + ch[p][3]);
            float tt = __builtin_fmaf(-2.0f, cross, r2v[p]);  // == fl(r2 - 2*cross), 2*cross exact
            float d2 = tt + c2m;
            if (d2 < best[p]) { best[p] = d2; bidx[p] = m; }
        }
    }

    // --- cross-lane argmin (ties -> smaller index), residual update ---
#pragma unroll 1
    for (int p = 0; p < 8; ++p) {
        float b = best[p];
        int ix = bidx[p];
#pragma unroll
        for (int off = 32; off >= 1; off >>= 1) {
            float ob = __shfl_xor(b, off);
            int oix = __shfl_xor(ix, off);
            if (ob < b || (ob == b && oix < ix)) { b = ob; ix = oix; }
        }
        const size_t prow = (size_t)(pbase + p) * DD;
        float q = cbk[(size_t)ix * DD + lane];
        res_out[prow + lane] = res_in[prow + lane] - q;   // exact elementwise fp32
        if (lane == 0) idx_out[pbase + p] = (float)ix;
    }
}

// ---- finalize: quantized = x - residual ----
__global__ __launch_bounds__(256) void rvq_final(const float* __restrict__ x,
                                                 const float* __restrict__ res,
                                                 float* __restrict__ q) {
#pragma clang fp contract(off)
    int i = blockIdx.x * 256 + threadIdx.x;
    q[i] = x[i] - res[i];
}

extern "C" void kernel_launch(void* const* d_in, const int* in_sizes, int n_in,
                              void* d_out, int out_size, void* d_ws, size_t ws_size,
                              hipStream_t stream) {
    const float* x  = (const float*)d_in[0];
    const float* cb = (const float*)d_in[1];

    float* out = (float*)d_out;
    float* quant = out;                 // QSIZE floats
    float* idx_out = out + QSIZE;       // K*NPTS floats (indices written as float)

    float* cbt  = (float*)d_ws;                       // K*D*M floats (4 MB)
    float* c2   = cbt + (size_t)KK * DD * MM;         // K*M floats
    float* res1 = c2 + (size_t)KK * MM;               // NPTS*D floats (8 MB)
    float* R[2] = { quant, res1 };                    // ping-pong residual (R0 lives in d_out)

    rvq_prep<<<(KK * MM) / 256, 256, 0, stream>>>(cb, cbt, c2);

    for (int k = 0; k < KK; ++k) {
        const float* rin = (k == 0) ? x : R[(k - 1) & 1];
        float* rout = R[k & 1];
        rvq_step<<<NPTS / 32, 256, 0, stream>>>(
            rin, rout,
            cb  + (size_t)k * MM * DD,
            cbt + (size_t)k * DD * MM,
            c2  + (size_t)k * MM,
            idx_out + (size_t)k * NPTS);
    }

    rvq_final<<<QSIZE / 256, 256, 0, stream>>>(x, R[(KK - 1) & 1], quant);
}

// Round 2
// 2109.601 us; speedup vs baseline: 11.1109x; 11.1109x over previous
//
#include <hip/hip_runtime.h>

// Residual VQ, bit-exact replication of the numpy reference's fp32 rounding.
// B=16 S=2048 D=64 K=8 M=2048.
//
// Numerics contract (verified bit-exact in R1, absmax 0.0):
//  - r2/c2: numpy pairwise_sum 8-accumulator order, no FMA contraction
//  - cross: numpy einsum baseline-SSE order: 4 chains (d mod 4), per 16-block
//           groups at offsets {12,8,4,0}+j, blocks ascending, hsum (L0+L1)+(L2+L3)
//  - t = fl(r2 - 2*cross) via fmaf(-2,cross,r2); d2 = fl(t + c2)
//  - argmin: first occurrence (strict <; cross-chunk combine in ascending-m
//    order with strict < preserves smallest-m ties)
//
// R2 structure: lane = point (residual register-resident, 64 VGPRs/lane),
// codebook address wave-uniform -> scalar/broadcast loads. 8 waves/block
// partition M into 256-m chunks; LDS argmin combine. No spills by design.

#define BB 16
#define SS 2048
#define DD 64
#define KK 8
#define MM 2048
#define NPTS (BB * SS)      // 32768
#define QSIZE (NPTS * DD)   // 2097152
#define WPB 8               // waves per block
#define MCHUNK (MM / WPB)   // 256 m per wave

// ---- prep: c2[k][m] (numpy pairwise) ----
__global__ __launch_bounds__(256) void rvq_prep(const float* __restrict__ cb,
                                                float* __restrict__ c2) {
#pragma clang fp contract(off)
    int tid = blockIdx.x * 256 + threadIdx.x;  // 0 .. K*M-1
    const float* row = cb + (size_t)tid * DD;
    float r[8];
#pragma unroll
    for (int j = 0; j < 8; ++j) { float v = row[j]; r[j] = v * v; }
#pragma unroll
    for (int i = 8; i < DD; i += 8) {
#pragma unroll
        for (int j = 0; j < 8; ++j) { float v = row[i + j]; float t = v * v; r[j] += t; }
    }
    c2[tid] = ((r[0] + r[1]) + (r[2] + r[3])) + ((r[4] + r[5]) + (r[6] + r[7]));
}

// ---- one RVQ step ----
// grid = NPTS/64 = 512 blocks x 512 threads (8 waves).
// lane = point within the block's 64-point group; wave = m-chunk.
__global__ __launch_bounds__(512) void rvq_step(const float* __restrict__ res_in,
                                                float* __restrict__ res_out,
                                                const float* __restrict__ cbk,  // (M,D) this k
                                                const float* __restrict__ c2k,  // (M,) this k
                                                float* __restrict__ idx_out) {  // (NPTS,) this k
#pragma clang fp contract(off)
    const int tid = threadIdx.x;
    const int lane = tid & 63;
    const int wv = __builtin_amdgcn_readfirstlane(tid >> 6);  // force wave-uniform
    const int point = blockIdx.x * 64 + lane;

    // --- load this lane's residual (64 floats) into registers, once ---
    float rv[DD];
    {
        const float4* rr4 = (const float4*)(res_in + (size_t)point * DD);
#pragma unroll
        for (int d4 = 0; d4 < DD / 4; ++d4) {
            float4 v = rr4[d4];
            rv[d4 * 4 + 0] = v.x; rv[d4 * 4 + 1] = v.y;
            rv[d4 * 4 + 2] = v.z; rv[d4 * 4 + 3] = v.w;
        }
    }

    // --- r2, numpy pairwise 8-accumulator order ---
    float r[8];
#pragma unroll
    for (int j = 0; j < 8; ++j) r[j] = rv[j] * rv[j];
#pragma unroll
    for (int i = 8; i < DD; i += 8) {
#pragma unroll
        for (int j = 0; j < 8; ++j) { float t = rv[i + j] * rv[i + j]; r[j] += t; }
    }
    const float r2 = ((r[0] + r[1]) + (r[2] + r[3])) + ((r[4] + r[5]) + (r[6] + r[7]));

    // --- scan this wave's m-chunk, lane-local argmin ---
    float best = __builtin_inff();
    int bidx = 0;
    const int m0 = wv * MCHUNK;
#pragma unroll 1
    for (int mi = 0; mi < MCHUNK; ++mi) {
        const int m = m0 + mi;
        const float4* crow4 = (const float4*)(cbk + (size_t)m * DD);  // wave-uniform addr
        const float c2m = c2k[m];
        float ch[4] = {0.0f, 0.0f, 0.0f, 0.0f};
        // einsum chain order: 16-blocks ascending; within, groups at offsets 12,8,4,0
#pragma unroll
        for (int b = 0; b < DD; b += 16) {
#pragma unroll
            for (int g = 3; g >= 0; --g) {
                const int d = b + g * 4;
                const float4 cv = crow4[d >> 2];
                { float tp = rv[d + 0] * cv.x; ch[0] += tp; }
                { float tp = rv[d + 1] * cv.y; ch[1] += tp; }
                { float tp = rv[d + 2] * cv.z; ch[2] += tp; }
                { float tp = rv[d + 3] * cv.w; ch[3] += tp; }
            }
        }
        const float cross = (ch[0] + ch[1]) + (ch[2] + ch[3]);
        const float tt = __builtin_fmaf(-2.0f, cross, r2);  // == fl(r2 - 2*cross)
        const float d2 = tt + c2m;
        if (d2 < best) { best = d2; bidx = m; }
    }

    // --- combine across the 8 m-chunks (waves), first-occurrence semantics ---
    __shared__ float sb[WPB * 64];
    __shared__ int   si[WPB * 64];
    __shared__ int   fidx[64];
    sb[wv * 64 + lane] = best;
    si[wv * 64 + lane] = bidx;
    __syncthreads();
    if (tid < 64) {
        float b = sb[lane];
        int ix = si[lane];
#pragma unroll
        for (int w = 1; w < WPB; ++w) {
            float ob = sb[w * 64 + lane];
            int oi = si[w * 64 + lane];
            if (ob < b) { b = ob; ix = oi; }  // strict <: earlier chunk (smaller m) wins ties
        }
        fidx[lane] = ix;
        idx_out[point] = (float)ix;  // exact for ix < 2^24
    }
    __syncthreads();

    // --- residual update: 512 threads x 8 elems, coalesced on res ---
    const size_t base = (size_t)blockIdx.x * 64 * DD;
#pragma unroll
    for (int i = 0; i < 8; ++i) {
        const int e = i * 512 + tid;
        const int p = e >> 6;
        const int d = e & 63;
        const int ix = fidx[p];
        res_out[base + e] = res_in[base + e] - cbk[(size_t)ix * DD + d];  // exact fp32 sub
    }
}

// ---- finalize: quantized = x - residual ----
__global__ __launch_bounds__(256) void rvq_final(const float* __restrict__ x,
                                                 const float* __restrict__ res,
                                                 float* __restrict__ q) {
#pragma clang fp contract(off)
    int i = blockIdx.x * 256 + threadIdx.x;
    q[i] = x[i] - res[i];
}

extern "C" void kernel_launch(void* const* d_in, const int* in_sizes, int n_in,
                              void* d_out, int out_size, void* d_ws, size_t ws_size,
                              hipStream_t stream) {
    const float* x  = (const float*)d_in[0];
    const float* cb = (const float*)d_in[1];

    float* out = (float*)d_out;
    float* quant = out;                 // QSIZE floats
    float* idx_out = out + QSIZE;       // K*NPTS floats (indices as float)

    float* c2   = (float*)d_ws;                       // K*M floats (64 KB)
    float* res1 = c2 + (size_t)KK * MM;               // NPTS*D floats (8 MB), 16B-aligned
    float* R[2] = { quant, res1 };                    // ping-pong residual (R0 in d_out)

    rvq_prep<<<(KK * MM) / 256, 256, 0, stream>>>(cb, c2);

    for (int k = 0; k < KK; ++k) {
        const float* rin = (k == 0) ? x : R[(k - 1) & 1];
        float* rout = R[k & 1];
        rvq_step<<<NPTS / 64, 512, 0, stream>>>(
            rin, rout,
            cb + (size_t)k * MM * DD,
            c2 + (size_t)k * MM,
            idx_out + (size_t)k * NPTS);
    }

    rvq_final<<<QSIZE / 256, 256, 0, stream>>>(x, R[(KK - 1) & 1], quant);
}

// Round 3
// 1374.347 us; speedup vs baseline: 17.0551x; 1.5350x over previous
//
#include <hip/hip_runtime.h>

// Residual VQ, bit-exact replication of the numpy reference's fp32 rounding.
// B=16 S=2048 D=64 K=8 M=2048.
//
// Numerics contract (verified bit-exact in R1/R2, absmax 0.0):
//  - r2/c2: numpy pairwise_sum 8-accumulator order, no FMA contraction
//  - cross: numpy einsum baseline-SSE order: 4 chains (d mod 4), per 16-block
//           groups at offsets {12,8,4,0}+j, blocks ascending, hsum (L0+L1)+(L2+L3)
//  - t = fl(r2 - 2*cross) via fmaf(-2,cross,r2); d2 = fl(t + c2)
//  - argmin: first occurrence (strict <; cross-chunk combine ascending-m)
//
// R3: (a) residual pinned in VGPRs via empty asm (R2's VGPR=48 proved the
// compiler was re-loading it from L1 inside the m-loop); (b) packed fp32
// (v_pk_mul_f32 / v_pk_add_f32 via float2 ext-vector math) — two independent
// IEEE-RN fp32 ops per inst, per-element rounding identical to scalar.

#define BB 16
#define SS 2048
#define DD 64
#define KK 8
#define MM 2048
#define NPTS (BB * SS)      // 32768
#define QSIZE (NPTS * DD)   // 2097152
#define WPB 8               // waves per block
#define MCHUNK (MM / WPB)   // 256 m per wave

typedef float v2f __attribute__((ext_vector_type(2)));

// ---- prep: c2[k][m] (numpy pairwise) ----
__global__ __launch_bounds__(256) void rvq_prep(const float* __restrict__ cb,
                                                float* __restrict__ c2) {
#pragma clang fp contract(off)
    int tid = blockIdx.x * 256 + threadIdx.x;  // 0 .. K*M-1
    const float* row = cb + (size_t)tid * DD;
    float r[8];
#pragma unroll
    for (int j = 0; j < 8; ++j) { float v = row[j]; r[j] = v * v; }
#pragma unroll
    for (int i = 8; i < DD; i += 8) {
#pragma unroll
        for (int j = 0; j < 8; ++j) { float v = row[i + j]; float t = v * v; r[j] += t; }
    }
    c2[tid] = ((r[0] + r[1]) + (r[2] + r[3])) + ((r[4] + r[5]) + (r[6] + r[7]));
}

// ---- one RVQ step ----
// grid = NPTS/64 = 512 blocks x 512 threads (8 waves).
// lane = point within the block's 64-point group; wave = m-chunk.
__global__ __launch_bounds__(512, 4) void rvq_step(const float* __restrict__ res_in,
                                                   float* __restrict__ res_out,
                                                   const float* __restrict__ cbk,  // (M,D)
                                                   const float* __restrict__ c2k,  // (M,)
                                                   float* __restrict__ idx_out) {  // (NPTS,)
#pragma clang fp contract(off)
    const int tid = threadIdx.x;
    const int lane = tid & 63;
    const int wv = __builtin_amdgcn_readfirstlane(tid >> 6);  // wave-uniform
    const int point = blockIdx.x * 64 + lane;

    // --- load this lane's residual as 32 float2 pairs, once ---
    v2f rp[DD / 2];
    {
        const v2f* rr2 = (const v2f*)(res_in + (size_t)point * DD);
#pragma unroll
        for (int i = 0; i < DD / 2; ++i) rp[i] = rr2[i];
    }

    // --- r2, numpy pairwise 8-accumulator order (pairs {j,j+1} packed) ---
    v2f A[4];
#pragma unroll
    for (int j = 0; j < 4; ++j) A[j] = rp[j] * rp[j];
#pragma unroll
    for (int i = 8; i < DD; i += 8) {
#pragma unroll
        for (int j = 0; j < 4; ++j) { v2f t = rp[i / 2 + j] * rp[i / 2 + j]; A[j] += t; }
    }
    const float r2 = ((A[0].x + A[0].y) + (A[1].x + A[1].y))
                   + ((A[2].x + A[2].y) + (A[3].x + A[3].y));

    // --- pin rp in VGPRs: forbid rematerialization/reload inside the m-loop ---
#pragma unroll
    for (int i = 0; i < DD / 2; ++i) asm volatile("" : "+v"(rp[i]));

    // --- scan this wave's m-chunk, lane-local argmin ---
    float best = __builtin_inff();
    int bidx = 0;
    const int m0 = wv * MCHUNK;
#pragma unroll 2
    for (int mi = 0; mi < MCHUNK; ++mi) {
        const int m = m0 + mi;
        const v2f* crow2 = (const v2f*)(cbk + (size_t)m * DD);  // wave-uniform -> s_load
        const float c2m = c2k[m];
        v2f ch01 = {0.0f, 0.0f};   // chains j=0,1
        v2f ch23 = {0.0f, 0.0f};   // chains j=2,3
        // einsum chain order: 16-blocks ascending; within, groups at offsets 12,8,4,0
#pragma unroll
        for (int b = 0; b < DD; b += 16) {
#pragma unroll
            for (int g = 3; g >= 0; --g) {
                const int d = b + g * 4;
                const v2f c01 = crow2[(d >> 1) + 0];
                const v2f c23 = crow2[(d >> 1) + 1];
                { v2f t = rp[(d >> 1) + 0] * c01; ch01 += t; }
                { v2f t = rp[(d >> 1) + 1] * c23; ch23 += t; }
            }
        }
        const float cross = (ch01.x + ch01.y) + (ch23.x + ch23.y);
        const float tt = __builtin_fmaf(-2.0f, cross, r2);  // == fl(r2 - 2*cross)
        const float d2 = tt + c2m;
        if (d2 < best) { best = d2; bidx = m; }
    }

    // --- combine across the 8 m-chunks (waves), first-occurrence semantics ---
    __shared__ float sb[WPB * 64];
    __shared__ int   si[WPB * 64];
    __shared__ int   fidx[64];
    sb[wv * 64 + lane] = best;
    si[wv * 64 + lane] = bidx;
    __syncthreads();
    if (tid < 64) {
        float b = sb[lane];
        int ix = si[lane];
#pragma unroll
        for (int w = 1; w < WPB; ++w) {
            float ob = sb[w * 64 + lane];
            int oi = si[w * 64 + lane];
            if (ob < b) { b = ob; ix = oi; }  // strict <: smaller-m chunk wins ties
        }
        fidx[lane] = ix;
        idx_out[point] = (float)ix;  // exact for ix < 2^24
    }
    __syncthreads();

    // --- residual update: 512 threads x 8 elems, coalesced on res ---
    const size_t base = (size_t)blockIdx.x * 64 * DD;
#pragma unroll
    for (int i = 0; i < 8; ++i) {
        const int e = i * 512 + tid;
        const int p = e >> 6;
        const int d = e & 63;
        const int ix = fidx[p];
        res_out[base + e] = res_in[base + e] - cbk[(size_t)ix * DD + d];  // exact fp32 sub
    }
}

// ---- finalize: quantized = x - residual ----
__global__ __launch_bounds__(256) void rvq_final(const float* __restrict__ x,
                                                 const float* __restrict__ res,
                                                 float* __restrict__ q) {
#pragma clang fp contract(off)
    int i = blockIdx.x * 256 + threadIdx.x;
    q[i] = x[i] - res[i];
}

extern "C" void kernel_launch(void* const* d_in, const int* in_sizes, int n_in,
                              void* d_out, int out_size, void* d_ws, size_t ws_size,
                              hipStream_t stream) {
    const float* x  = (const float*)d_in[0];
    const float* cb = (const float*)d_in[1];

    float* out = (float*)d_out;
    float* quant = out;                 // QSIZE floats
    float* idx_out = out + QSIZE;       // K*NPTS floats (indices as float)

    float* c2   = (float*)d_ws;                       // K*M floats (64 KB)
    float* res1 = c2 + (size_t)KK * MM;               // NPTS*D floats (8 MB), 16B-aligned
    float* R[2] = { quant, res1 };                    // ping-pong residual (R0 in d_out)

    rvq_prep<<<(KK * MM) / 256, 256, 0, stream>>>(cb, c2);

    for (int k = 0; k < KK; ++k) {
        const float* rin = (k == 0) ? x : R[(k - 1) & 1];
        float* rout = R[k & 1];
        rvq_step<<<NPTS / 64, 512, 0, stream>>>(
            rin, rout,
            cb + (size_t)k * MM * DD,
            c2 + (size_t)k * MM,
            idx_out + (size_t)k * NPTS);
    }

    rvq_final<<<QSIZE / 256, 256, 0, stream>>>(x, R[(KK - 1) & 1], quant);
}